// Round 6
// baseline (161.594 us; speedup 1.0000x reference)
//
#include <hip/hip_runtime.h>
#include <hip/hip_bf16.h>

#define GAT_N 8192
#define GAT_K 256
#define GAT_D 64
#define GAT_ALPHA 0.2f
#define GAT_FILL 1e-15f

typedef float f32x4 __attribute__((ext_vector_type(4)));
typedef short bf16x8 __attribute__((ext_vector_type(8)));
typedef short bf16x4 __attribute__((ext_vector_type(4)));

static __device__ __forceinline__ unsigned f2bf_u(float x) {
  unsigned u = __float_as_uint(x);
  u += 0x7FFFu + ((u >> 16) & 1u);
  return u >> 16;
}

static __device__ __forceinline__ float rfl(float x) {
  return __uint_as_float(__builtin_amdgcn_readfirstlane(__float_as_uint(x)));
}

// inverse-ballot select: res[lane] = (bit `lane` of w) ? pe : cc
static __device__ __forceinline__ float bitsel(unsigned long long w, float pe,
                                               float cc) {
  float res;
  asm("v_cndmask_b32 %0, %1, %2, %3" : "=v"(res) : "v"(cc), "v"(pe), "s"(w));
  return res;
}

#define PREP_BLOCKS 512
#define CMP_BLOCKS 2048

// ---------------------------------------------------------------------------
// Kernel 0 (fused, 2560 blocks x 256 threads):
//  blocks [0,512):     prep  — Wh=h@W, WhT bf16[D][N], s_src/s_dst, bmax
//  blocks [512,2560):  compress — A -> 1-bit adjacency mask via __ballot.
//    One row per wave (32 KB contiguous stream, 4 ballots per 1 KB load).
//    This is the ONLY pass that reads A (256 MB); it is fill-shaped.
//  mask layout: word[row*128 + g*4 + e] bit l  <->  A[row][g*256 + l*4 + e]
// ---------------------------------------------------------------------------
__global__ __launch_bounds__(256) void k0_fused(
    const float* __restrict__ A, const float* __restrict__ h,
    const float* __restrict__ W, const float* __restrict__ av,
    unsigned long long* __restrict__ mask, float* __restrict__ s_src,
    float* __restrict__ s_dst, short* __restrict__ WhT,
    float* __restrict__ bmax) {
  const int tid = threadIdx.x;
  const int wv = tid >> 6, lane = tid & 63;

  if (blockIdx.x >= PREP_BLOCKS) {
    // ---- compress branch ----
    const int row = (blockIdx.x - PREP_BLOCKS) * 4 + wv;
    const float* p = A + (size_t)row * GAT_N + lane * 4;
    unsigned long long* mrow = mask + (size_t)row * 128;
    f32x4 cur = __builtin_nontemporal_load((const f32x4*)p);
#pragma unroll 4
    for (int g = 0; g < 32; ++g) {
      f32x4 nxt;
      if (g < 31)
        nxt = __builtin_nontemporal_load((const f32x4*)(p + (g + 1) * 256));
      unsigned long long b0 = __ballot(cur[0] > 0.f);
      unsigned long long b1 = __ballot(cur[1] > 0.f);
      unsigned long long b2 = __ballot(cur[2] > 0.f);
      unsigned long long b3 = __ballot(cur[3] > 0.f);
      if (lane < 4) {
        unsigned long long w = (lane == 0) ? b0 : (lane == 1) ? b1 : (lane == 2) ? b2 : b3;
        mrow[g * 4 + lane] = w;
      }
      cur = nxt;
    }
    return;
  }

  // ---- prep branch (register-tiled Wh = h @ W; 4 rows per wave) ----
  __shared__ float wmLds[4];
  const int r0 = blockIdx.x * 16 + wv * 4;

  float acc[4], acc2[4];
#pragma unroll
  for (int r = 0; r < 4; ++r) { acc[r] = 0.f; acc2[r] = 0.f; }

  for (int kc = 0; kc < GAT_K; kc += 32) {
    float Wreg[32];
#pragma unroll
    for (int e = 0; e < 32; ++e) Wreg[e] = W[(size_t)(kc + e) * GAT_D + lane];
#pragma unroll
    for (int r = 0; r < 4; ++r) {
      const f32x4* h4 = (const f32x4*)(h + (size_t)(r0 + r) * GAT_K + kc);
#pragma unroll
      for (int q = 0; q < 8; ++q) {
        f32x4 hv = h4[q];
        acc[r] += hv[0] * Wreg[4 * q + 0];
        acc2[r] += hv[1] * Wreg[4 * q + 1];
        acc[r] += hv[2] * Wreg[4 * q + 2];
        acc2[r] += hv[3] * Wreg[4 * q + 3];
      }
    }
  }

  const float a_s = av[lane];
  const float a_d = av[64 + lane];
  float wmax = -3.0e38f;
  bf16x4 vt;
#pragma unroll
  for (int r = 0; r < 4; ++r) {
    const float accf = acc[r] + acc2[r];
    vt[r] = (short)f2bf_u(accf);
    float vs = accf * a_s, vd = accf * a_d;
#pragma unroll
    for (int off = 32; off > 0; off >>= 1) {
      vs += __shfl_xor(vs, off);
      vd += __shfl_xor(vd, off);
    }
    if (lane == 0) { s_src[r0 + r] = vs; s_dst[r0 + r] = vd; }
    wmax = fmaxf(wmax, vd);
  }
  *(bf16x4*)(WhT + (size_t)lane * GAT_N + r0) = vt;  // WhT[d=lane][r0..r0+3]

  if (lane == 0) wmLds[wv] = wmax;
  __syncthreads();
  if (tid == 0) {
    bmax[blockIdx.x] = fmaxf(fmaxf(wmLds[0], wmLds[1]), fmaxf(wmLds[2], wmLds[3]));
  }
}

// ---------------------------------------------------------------------------
// Kernel 2: fused masked-softmax + P@Wh, fixed-shift softmax. NO A reads —
// adjacency comes from the 8 MB bitmask (wave-uniform s_loads, L2/L3-hit),
// applied via inverse-ballot v_cndmask (1 VALU/elem). Stage phase writes the
// XOR-swizzled [16][2048] bf16 P tile; MFMA phase: each wave consumes its
// disjoint 256-col slice (8 kq x 5 MFMAs, +ones B for the row-sum). Exact
// cross-wave combine at the end (fixed shift => partials add exactly).
// ---------------------------------------------------------------------------
#define BM 16
#define JB 2048
#define NWAVE 8

__global__ __launch_bounds__(512, 4) void k_attn(
    const unsigned long long* __restrict__ mask,
    const float* __restrict__ s_src,
    const float* __restrict__ s_dst,
    const short* __restrict__ WhT,
    const float* __restrict__ bmax,
    float* __restrict__ out) {
  __shared__ char smem[65536];  // P tile [16][2048] bf16 (swizzled); epilogue reuse

  const int tid = threadIdx.x;
  const int wv = tid >> 6, lane = tid & 63;
  const int wvu = __builtin_amdgcn_readfirstlane(wv);  // provably uniform
  const int rsub = lane & 15, kg = lane >> 4;
  const int i0 = blockIdx.x * BM;

  // global max of s_dst from 512 per-block maxima
  float bm = -3.0e38f;
#pragma unroll
  for (int k = 0; k < 8; ++k) bm = fmaxf(bm, bmax[lane + 64 * k]);
#pragma unroll
  for (int off = 32; off > 0; off >>= 1) bm = fmaxf(bm, __shfl_xor(bm, off));
  const float tmax = bm;

  // per-row (wave-uniform) softmax constants in SGPRs:
  //   P = exp(max(t + e1, 0.2t + e2)) if edge else exp(FILL - mhat)
  float e1_[BM], e2_[BM], c_[BM];
#pragma unroll
  for (int r = 0; r < BM; ++r) {
    float s = s_src[i0 + r];
    float x0 = s + tmax;
    float m = fmaxf(fmaxf(x0, GAT_ALPHA * x0), GAT_FILL);
    e1_[r] = rfl(s - m);
    e2_[r] = rfl(GAT_ALPHA * s - m);
    c_[r] = rfl(__expf(GAT_FILL - m));
  }

  bf16x8 ones;
#pragma unroll
  for (int e = 0; e < 8; ++e) ones[e] = (short)0x3F80;

  f32x4 acc0 = {0.f, 0.f, 0.f, 0.f};
  f32x4 acc1 = {0.f, 0.f, 0.f, 0.f};
  f32x4 acc2 = {0.f, 0.f, 0.f, 0.f};
  f32x4 acc3 = {0.f, 0.f, 0.f, 0.f};
  f32x4 accl = {0.f, 0.f, 0.f, 0.f};

  const short* pb0 = WhT + (size_t)(0 * 16 + rsub) * GAT_N;
  const short* pb1 = WhT + (size_t)(1 * 16 + rsub) * GAT_N;
  const short* pb2 = WhT + (size_t)(2 * 16 + rsub) * GAT_N;
  const short* pb3 = WhT + (size_t)(3 * 16 + rsub) * GAT_N;

  for (int chunk = 0; chunk < GAT_N / JB; ++chunk) {
    const int jc = chunk * JB;
    const f32x4 t = *(const f32x4*)(s_dst + jc + tid * 4);  // reused for 16 rows

    // ---- stage phase: P from bitmask, no global A traffic ----
#pragma unroll
    for (int r = 0; r < BM; ++r) {
      const unsigned long long* mw =
          mask + (size_t)(i0 + r) * 128 + (size_t)(chunk * 8 + wvu) * 4;
      unsigned long long w0 = mw[0], w1 = mw[1], w2 = mw[2], w3 = mw[3];
      const float e1 = e1_[r], e2 = e2_[r], cc = c_[r];
      unsigned pk[4];
      {
        float pe = __expf(fmaxf(t[0] + e1, fmaf(GAT_ALPHA, t[0], e2)));
        pk[0] = f2bf_u(bitsel(w0, pe, cc));
      }
      {
        float pe = __expf(fmaxf(t[1] + e1, fmaf(GAT_ALPHA, t[1], e2)));
        pk[1] = f2bf_u(bitsel(w1, pe, cc));
      }
      {
        float pe = __expf(fmaxf(t[2] + e1, fmaf(GAT_ALPHA, t[2], e2)));
        pk[2] = f2bf_u(bitsel(w2, pe, cc));
      }
      {
        float pe = __expf(fmaxf(t[3] + e1, fmaf(GAT_ALPHA, t[3], e2)));
        pk[3] = f2bf_u(bitsel(w3, pe, cc));
      }
      uint2 w;
      w.x = pk[0] | (pk[1] << 16);
      w.y = pk[2] | (pk[3] << 16);
      *(uint2*)(&smem[(r << 12) + ((tid << 3) ^ ((r & 7) << 4))]) = w;
    }
    __syncthreads();

    // ---- MFMA phase: wave wv consumes cols [jc + wv*256, +256) ----
#pragma unroll
    for (int kq = 0; kq < 8; ++kq) {
      const int cbyte = (wv << 9) + (kq << 6) + (kg << 4);
      bf16x8 af = *(const bf16x8*)(&smem[(rsub << 12) + (cbyte ^ ((rsub & 7) << 4))]);
      const int bcol = jc + (wv << 8) + (kq << 5) + (kg << 3);
      bf16x8 b0 = *(const bf16x8*)(pb0 + bcol);
      bf16x8 b1 = *(const bf16x8*)(pb1 + bcol);
      bf16x8 b2 = *(const bf16x8*)(pb2 + bcol);
      bf16x8 b3 = *(const bf16x8*)(pb3 + bcol);
      acc0 = __builtin_amdgcn_mfma_f32_16x16x32_bf16(af, b0, acc0, 0, 0, 0);
      acc1 = __builtin_amdgcn_mfma_f32_16x16x32_bf16(af, b1, acc1, 0, 0, 0);
      acc2 = __builtin_amdgcn_mfma_f32_16x16x32_bf16(af, b2, acc2, 0, 0, 0);
      acc3 = __builtin_amdgcn_mfma_f32_16x16x32_bf16(af, b3, acc3, 0, 0, 0);
      accl = __builtin_amdgcn_mfma_f32_16x16x32_bf16(af, ones, accl, 0, 0, 0);
    }
    __syncthreads();  // protect tile before next stage overwrites
  }

  // ---- epilogue: exact cross-wave combine + ELU (smem reused) ----
  float* lds_o = (float*)smem;            // [8][16][64] f32 = 32 KB
  float* lds_l = (float*)(smem + 32768);  // [8][16]
#pragma unroll
  for (int r = 0; r < 4; ++r) {
    const int orow = kg * 4 + r;  // C/D layout: col = lane&15, row = kg*4+reg
    lds_o[wv * 1024 + orow * 64 + 0 * 16 + rsub] = acc0[r];
    lds_o[wv * 1024 + orow * 64 + 1 * 16 + rsub] = acc1[r];
    lds_o[wv * 1024 + orow * 64 + 2 * 16 + rsub] = acc2[r];
    lds_o[wv * 1024 + orow * 64 + 3 * 16 + rsub] = acc3[r];
    if (rsub == 0) lds_l[wv * 16 + orow] = accl[r];
  }
  __syncthreads();

  for (int idx = tid; idx < BM * GAT_D; idx += 512) {
    const int r = idx >> 6, c = idx & 63;
    float o = 0.f, ll = 0.f;
#pragma unroll
    for (int w = 0; w < NWAVE; ++w) {
      o += lds_o[w * 1024 + r * 64 + c];
      ll += lds_l[w * 16 + r];
    }
    float val = o / ll;
    out[(size_t)(i0 + r) * GAT_D + c] = (val > 0.f) ? val : (__expf(val) - 1.f);
  }
}

// ---------------------------------------------------------------------------
extern "C" void kernel_launch(void* const* d_in, const int* in_sizes, int n_in,
                              void* d_out, int out_size, void* d_ws, size_t ws_size,
                              hipStream_t stream) {
  const float* h = (const float*)d_in[0];
  const float* A = (const float*)d_in[1];
  const float* W = (const float*)d_in[2];
  const float* a = (const float*)d_in[3];
  float* out = (float*)d_out;

  // ws: [0,2K) bmax | [4K,+32K) s_src | [36864,+32K) s_dst | [69632,+1M) WhT
  //     [1179648,+8M) adjacency bitmask
  const size_t need = 1179648 + (size_t)GAT_N * 128 * 8;
  if (ws_size < need) return;
  float* bmax = (float*)d_ws;
  float* s_src = (float*)((char*)d_ws + 4096);
  float* s_dst = (float*)((char*)d_ws + 36864);
  short* WhT = (short*)((char*)d_ws + 69632);
  unsigned long long* mask = (unsigned long long*)((char*)d_ws + 1179648);

  k0_fused<<<dim3(PREP_BLOCKS + CMP_BLOCKS), dim3(256), 0, stream>>>(
      A, h, W, a, mask, s_src, s_dst, WhT, bmax);
  k_attn<<<dim3(GAT_N / BM), dim3(512), 0, stream>>>(mask, s_src, s_dst, WhT,
                                                     bmax, out);
}

// Round 7
// 136.663 us; speedup vs baseline: 1.1824x; 1.1824x over previous
//
#include <hip/hip_runtime.h>
#include <hip/hip_bf16.h>

#define GAT_N 8192
#define GAT_K 256
#define GAT_D 64
#define GAT_ALPHA 0.2f
#define GAT_FILL 1e-15f

typedef float f32x4 __attribute__((ext_vector_type(4)));
typedef short bf16x8 __attribute__((ext_vector_type(8)));

static __device__ __forceinline__ unsigned f2bf_u(float x) {
  unsigned u = __float_as_uint(x);
  u += 0x7FFFu + ((u >> 16) & 1u);
  return u >> 16;
}

static __device__ __forceinline__ float rfl(float x) {
  return __uint_as_float(__builtin_amdgcn_readfirstlane(__float_as_uint(x)));
}

// ---------------------------------------------------------------------------
// Kernel 1: register-tiled Wh = h @ W (validated in round 4, unchanged).
// ---------------------------------------------------------------------------
__global__ __launch_bounds__(256) void k_prep(const float* __restrict__ h,
                                              const float* __restrict__ W,
                                              const float* __restrict__ av,
                                              float* __restrict__ s_src,
                                              float* __restrict__ s_dst,
                                              short* __restrict__ WhT,
                                              float* __restrict__ bmax) {
  __shared__ short T[4][64][8];
  __shared__ float wmLds[4];
  const int tid = threadIdx.x;
  const int wv = tid >> 6, lane = tid & 63;
  const int r0 = blockIdx.x * 32 + wv * 8;

  float acc[8], acc2[8];
#pragma unroll
  for (int r = 0; r < 8; ++r) { acc[r] = 0.f; acc2[r] = 0.f; }

  for (int kc = 0; kc < GAT_K; kc += 32) {
    float Wreg[32];
#pragma unroll
    for (int e = 0; e < 32; ++e) Wreg[e] = W[(size_t)(kc + e) * GAT_D + lane];
#pragma unroll
    for (int r = 0; r < 8; ++r) {
      const f32x4* h4 = (const f32x4*)(h + (size_t)(r0 + r) * GAT_K + kc);
#pragma unroll
      for (int q = 0; q < 8; ++q) {
        f32x4 hv = h4[q];
        acc[r] += hv[0] * Wreg[4 * q + 0];
        acc2[r] += hv[1] * Wreg[4 * q + 1];
        acc[r] += hv[2] * Wreg[4 * q + 2];
        acc2[r] += hv[3] * Wreg[4 * q + 3];
      }
    }
  }

  const float a_s = av[lane];
  const float a_d = av[64 + lane];
  float wmax = -3.0e38f;
#pragma unroll
  for (int r = 0; r < 8; ++r) {
    const float accf = acc[r] + acc2[r];
    T[wv][lane][r] = (short)f2bf_u(accf);
    float vs = accf * a_s, vd = accf * a_d;
#pragma unroll
    for (int off = 32; off > 0; off >>= 1) {
      vs += __shfl_xor(vs, off);
      vd += __shfl_xor(vd, off);
    }
    if (lane == 0) { s_src[r0 + r] = vs; s_dst[r0 + r] = vd; }
    wmax = fmaxf(wmax, vd);
  }
  bf16x8 vt = *(const bf16x8*)&T[wv][lane][0];
  *(bf16x8*)(WhT + (size_t)lane * GAT_N + r0) = vt;

  if (lane == 0) wmLds[wv] = wmax;
  __syncthreads();
  if (tid == 0) {
    bmax[blockIdx.x] = fmaxf(fmaxf(wmLds[0], wmLds[1]), fmaxf(wmLds[2], wmLds[3]));
  }
}

// ---------------------------------------------------------------------------
// Kernel 2: fused masked-softmax + P@Wh, fixed-shift softmax.
// Block = 16 rows; chunks of 1024 cols; DOUBLE-BUFFERED P tile (2 x 32 KB,
// XOR-swizzled) -> ONE barrier per chunk, stage(c+1) overlaps MFMA(c) across
// waves. A loads are PLAIN (cacheable: A is exactly L3-sized and persists
// across replays). In-chunk 4-deep load pipeline (16 VGPRs), preissue across
// the chunk boundary. Accumulation order identical to round 4.
// Threads 0-255 stage even rows, 256-511 odd rows (wave-uniform parity).
// ---------------------------------------------------------------------------
#define BM 16
#define JB 1024
#define NCHUNK (GAT_N / JB)
#define NWAVE 8

__global__ __launch_bounds__(512, 4) void k_attn(
    const float* __restrict__ A,
    const float* __restrict__ s_src,
    const float* __restrict__ s_dst,
    const short* __restrict__ WhT,
    const float* __restrict__ bmax,
    float* __restrict__ out) {
  __shared__ char smem[65536];  // 2 x [16][1024] bf16 swizzled tiles; epilogue reuse

  const int tid = threadIdx.x;
  const int wv = tid >> 6, lane = tid & 63;
  const int rsub = lane & 15, kg = lane >> 4;
  const int i0 = blockIdx.x * BM;
  const int par = wv >> 2;          // wave-uniform: 0 for tid<256, 1 for tid>=256
  const int cth = tid & 255;        // column-thread index within parity group

  // global max of s_dst from 256 per-block maxima
  float bm = fmaxf(fmaxf(bmax[lane], bmax[lane + 64]),
                   fmaxf(bmax[lane + 128], bmax[lane + 192]));
#pragma unroll
  for (int off = 32; off > 0; off >>= 1) bm = fmaxf(bm, __shfl_xor(bm, off));
  const float tmax = bm;

  // softmax constants for this thread's 8 rows (row = 2*s + par, wave-uniform)
  float e1_[8], e2_[8], c_[8];
#pragma unroll
  for (int s = 0; s < 8; ++s) {
    float sc = s_src[i0 + 2 * s + par];
    float x0 = sc + tmax;
    float m = fmaxf(fmaxf(x0, GAT_ALPHA * x0), GAT_FILL);
    e1_[s] = rfl(sc - m);
    e2_[s] = rfl(GAT_ALPHA * sc - m);
    c_[s] = rfl(__expf(GAT_FILL - m));
  }

  bf16x8 ones;
#pragma unroll
  for (int e = 0; e < 8; ++e) ones[e] = (short)0x3F80;

  f32x4 acc0 = {0.f, 0.f, 0.f, 0.f};
  f32x4 acc1 = {0.f, 0.f, 0.f, 0.f};
  f32x4 acc2 = {0.f, 0.f, 0.f, 0.f};
  f32x4 acc3 = {0.f, 0.f, 0.f, 0.f};
  f32x4 accl = {0.f, 0.f, 0.f, 0.f};

  const short* pb0 = WhT + (size_t)(0 * 16 + rsub) * GAT_N;
  const short* pb1 = WhT + (size_t)(1 * 16 + rsub) * GAT_N;
  const short* pb2 = WhT + (size_t)(2 * 16 + rsub) * GAT_N;
  const short* pb3 = WhT + (size_t)(3 * 16 + rsub) * GAT_N;

  // A addressing: global step g (0..63): chunk g>>3, in-chunk step s=g&7,
  // this thread's row = 2*s + par, cols [chunk*1024 + cth*4, +4)
  const float* Abase = A + (size_t)(i0 + par) * GAT_N + cth * 4;
  auto aaddr = [&](int g) {
    return Abase + (size_t)((g & 7) * 2) * GAT_N + (g >> 3) * JB;
  };

  f32x4 buf[4];
#pragma unroll
  for (int g = 0; g < 4; ++g) buf[g] = *(const f32x4*)aaddr(g);

  for (int chunk = 0; chunk < NCHUNK; ++chunk) {
    const int jc = chunk * JB;
    const int tile = (chunk & 1) << 15;  // 0 or 32768
    const f32x4 t = *(const f32x4*)(s_dst + jc + cth * 4);

    // ---- stage phase: 8 steps, 4-deep pipeline ----
#pragma unroll
    for (int s = 0; s < 8; ++s) {
      const int g = chunk * 8 + s;
      f32x4 av = buf[g & 3];
      if (g + 4 < 64) buf[(g + 4) & 3] = *(const f32x4*)aaddr(g + 4);
      const float e1 = e1_[s], e2 = e2_[s], cc = c_[s];
      unsigned pk[4];
#pragma unroll
      for (int e = 0; e < 4; ++e) {
        float arg = fmaxf(t[e] + e1, fmaf(GAT_ALPHA, t[e], e2));
        float pe = __expf(arg);
        pe = (av[e] > 0.f) ? pe : cc;
        pk[e] = f2bf_u(pe);
      }
      uint2 w;
      w.x = pk[0] | (pk[1] << 16);
      w.y = pk[2] | (pk[3] << 16);
      const int row = 2 * s + par;
      *(uint2*)(&smem[tile + (row << 11) + (((cth << 3)) ^ ((row & 7) << 4))]) = w;
    }
    __syncthreads();  // tile ready; also orders MFMA(c-1) before stage(c+1)

    // ---- MFMA phase: wave wv consumes cols [jc + wv*128, +128) ----
#pragma unroll
    for (int kq = 0; kq < 4; ++kq) {
      const int cbyte = (wv << 8) + (kq << 6) + (kg << 4);
      bf16x8 af = *(const bf16x8*)(&smem[tile + (rsub << 11) + (cbyte ^ ((rsub & 7) << 4))]);
      const int bcol = jc + (wv << 7) + (kq << 5) + (kg << 3);
      bf16x8 b0 = *(const bf16x8*)(pb0 + bcol);
      bf16x8 b1 = *(const bf16x8*)(pb1 + bcol);
      bf16x8 b2 = *(const bf16x8*)(pb2 + bcol);
      bf16x8 b3 = *(const bf16x8*)(pb3 + bcol);
      acc0 = __builtin_amdgcn_mfma_f32_16x16x32_bf16(af, b0, acc0, 0, 0, 0);
      acc1 = __builtin_amdgcn_mfma_f32_16x16x32_bf16(af, b1, acc1, 0, 0, 0);
      acc2 = __builtin_amdgcn_mfma_f32_16x16x32_bf16(af, b2, acc2, 0, 0, 0);
      acc3 = __builtin_amdgcn_mfma_f32_16x16x32_bf16(af, b3, acc3, 0, 0, 0);
      accl = __builtin_amdgcn_mfma_f32_16x16x32_bf16(af, ones, accl, 0, 0, 0);
    }
    // no trailing barrier: next stage writes the OTHER tile; the barrier in
    // the next iteration orders this MFMA before the re-stage of this tile.
  }

  __syncthreads();  // all MFMA done before smem reuse

  // ---- epilogue: exact cross-wave combine + ELU (smem reused) ----
  float* lds_o = (float*)smem;            // [8][16][64] f32 = 32 KB
  float* lds_l = (float*)(smem + 32768);  // [8][16]
#pragma unroll
  for (int r = 0; r < 4; ++r) {
    const int orow = kg * 4 + r;  // C/D layout: col = lane&15, row = kg*4+reg
    lds_o[wv * 1024 + orow * 64 + 0 * 16 + rsub] = acc0[r];
    lds_o[wv * 1024 + orow * 64 + 1 * 16 + rsub] = acc1[r];
    lds_o[wv * 1024 + orow * 64 + 2 * 16 + rsub] = acc2[r];
    lds_o[wv * 1024 + orow * 64 + 3 * 16 + rsub] = acc3[r];
    if (rsub == 0) lds_l[wv * 16 + orow] = accl[r];
  }
  __syncthreads();

  for (int idx = tid; idx < BM * GAT_D; idx += 512) {
    const int r = idx >> 6, c = idx & 63;
    float o = 0.f, ll = 0.f;
#pragma unroll
    for (int w = 0; w < NWAVE; ++w) {
      o += lds_o[w * 1024 + r * 64 + c];
      ll += lds_l[w * 16 + r];
    }
    float val = o / ll;
    out[(size_t)(i0 + r) * GAT_D + c] = (val > 0.f) ? val : (__expf(val) - 1.f);
  }
}

// ---------------------------------------------------------------------------
extern "C" void kernel_launch(void* const* d_in, const int* in_sizes, int n_in,
                              void* d_out, int out_size, void* d_ws, size_t ws_size,
                              hipStream_t stream) {
  const float* h = (const float*)d_in[0];
  const float* A = (const float*)d_in[1];
  const float* W = (const float*)d_in[2];
  const float* a = (const float*)d_in[3];
  float* out = (float*)d_out;

  // ws layout: [0,1K) bmax | [4K,+32K) s_src | [36864,+32K) s_dst | [69632,+1M) WhT
  const size_t need = 69632 + (size_t)GAT_D * GAT_N * 2;
  if (ws_size < need) return;
  float* bmax = (float*)d_ws;
  float* s_src = (float*)((char*)d_ws + 4096);
  float* s_dst = (float*)((char*)d_ws + 36864);
  short* WhT = (short*)((char*)d_ws + 69632);

  k_prep<<<dim3(256), dim3(256), 0, stream>>>(h, W, a, s_src, s_dst, WhT, bmax);
  k_attn<<<dim3(GAT_N / BM), dim3(512), 0, stream>>>(A, s_src, s_dst, WhT, bmax, out);
}